// Round 1
// baseline (713.476 us; speedup 1.0000x reference)
//
#include <hip/hip_runtime.h>
#include <cstdint>
#include <math.h>

// EnergyCAModel: 4-step neural CA.
// Layouts: x [B=16,H=128,W=128,C=16] f32. Out = x_steps [4*16*128*128*16] ++ fr_steps [4*16*128*128].
#define HW2    16384      // 128*128
#define BHW    262144     // 16*128*128
#define XSLICE 4194304    // BHW*16

// 1 = modern JAX (jax_threefry_partitionable=True, default since 0.4.36)
// 0 = legacy threefry counter layout
#define PARTITIONABLE 1

__host__ __device__ static inline uint32_t rotl32(uint32_t v, int r) {
  return (v << r) | (v >> (32 - r));
}

// Exact JAX Threefry-2x32 (20 rounds).
__host__ __device__ static inline void tf2x32(uint32_t k0, uint32_t k1,
                                              uint32_t x0, uint32_t x1,
                                              uint32_t& o0, uint32_t& o1) {
  uint32_t ks2 = k0 ^ k1 ^ 0x1BD11BDAu;
  x0 += k0; x1 += k1;
#define TFR(r) { x0 += x1; x1 = rotl32(x1, (r)); x1 ^= x0; }
  TFR(13) TFR(15) TFR(26) TFR(6)   x0 += k1;  x1 += ks2 + 1u;
  TFR(17) TFR(29) TFR(16) TFR(24)  x0 += ks2; x1 += k0 + 2u;
  TFR(13) TFR(15) TFR(26) TFR(6)   x0 += k0;  x1 += k1 + 3u;
  TFR(17) TFR(29) TFR(16) TFR(24)  x0 += k1;  x1 += ks2 + 4u;
  TFR(13) TFR(15) TFR(26) TFR(6)   x0 += ks2; x1 += k0 + 5u;
#undef TFR
  o0 = x0; o1 = x1;
}

__device__ static inline float bits_to_unit(uint32_t bits) {
  // jax.random.uniform: bitcast((bits>>9)|0x3f800000) - 1.0  -> [0,1)
  return __uint_as_float((bits >> 9) | 0x3f800000u) - 1.0f;
}

// random bits for flat element f of a 524288-element uniform draw
__device__ static inline uint32_t rng_bits(uint32_t sk0, uint32_t sk1, uint32_t f) {
  uint32_t o0, o1;
#if PARTITIONABLE
  tf2x32(sk0, sk1, 0u, f, o0, o1);
  return o0 ^ o1;
#else
  const uint32_t half = 262144u;
  uint32_t c = (f < half) ? f : (f - half);
  tf2x32(sk0, sk1, c, c + half, o0, o1);
  return (f < half) ? o0 : o1;
#endif
}

__device__ static inline float sigmoidf_(float z) {
  if (z >= 0.f) { float e = expf(-z); return 1.f / (1.f + e); }
  float e = expf(z); return e / (1.f + e);
}

// Kernel A: per pixel -> sobel features, pre-alive, fr, gumbel gate, MLP, x_mid.
__global__ __launch_bounds__(256) void ca_step_a(
    const float* __restrict__ xin,   // [B,H,W,16]
    const float* __restrict__ w0g,   // [256,48]
    const float* __restrict__ b0g,   // [256]
    const float* __restrict__ w1t,   // [256,16]  (w1 transposed)
    const float* __restrict__ wfrg,  // [48]
    float* __restrict__ xmid,        // d_out x-slice for this step
    float* __restrict__ ch3,         // [BHW] updated channel-3 plane
    float* __restrict__ premask,     // [BHW]
    float* __restrict__ frout,       // [BHW] fr output slice
    uint32_t sk0, uint32_t sk1) {
  __shared__ float sw0[256 * 48];
  __shared__ float sb0[256];
  __shared__ float swfr[48];
  const int tid = threadIdx.x;
  {
    const float4* src = (const float4*)w0g;
    float4* dst = (float4*)sw0;
    for (int i = tid; i < 256 * 12; i += 256) dst[i] = src[i];
    sb0[tid] = b0g[tid];
    if (tid < 48) swfr[tid] = wfrg[tid];
  }
  __syncthreads();

  const int p   = blockIdx.x * 256 + tid;
  const int b   = p >> 14;
  const int rem = p & 16383;
  const int hh  = rem >> 7;
  const int ww  = rem & 127;

  // dxv = [x(16), y1(16), y2(16)]
  float dxv[48];
#pragma unroll
  for (int c = 0; c < 48; ++c) dxv[c] = 0.f;
  float m3 = -INFINITY;

  const float* base = xin + ((size_t)b << 18);
#pragma unroll
  for (int dh = -1; dh <= 1; ++dh) {
    const int j = dh + 1;              // H kernel index
    const int h2 = hh + dh;
    const bool hok = ((unsigned)h2 < 128u);
#pragma unroll
    for (int dw = -1; dw <= 1; ++dw) {
      const int i = dw + 1;            // W kernel index
      const int w2 = ww + dw;
      float v[16];
      if (hok && ((unsigned)w2 < 128u)) {
        const float* s = base + (((h2 << 7) + w2) << 4);
#pragma unroll
        for (int c = 0; c < 16; c += 4) {
          float4 q = *(const float4*)(s + c);
          v[c] = q.x; v[c + 1] = q.y; v[c + 2] = q.z; v[c + 3] = q.w;
        }
        m3 = fmaxf(m3, v[3]);
      } else {
#pragma unroll
        for (int c = 0; c < 16; ++c) v[c] = 0.f;
      }
      // y1: smooth[1,2,1] over W, diff[-1,0,1] over H;  y2: transposed (angle=0)
      const float smv[3] = {1.f, 2.f, 1.f};
      const float dfv[3] = {-1.f, 0.f, 1.f};
      const float c1 = smv[i] * dfv[j] * 0.125f;
      const float c2 = dfv[i] * smv[j] * 0.125f;
      if (dh == 0 && dw == 0) {
#pragma unroll
        for (int c = 0; c < 16; ++c) dxv[c] = v[c];
      }
      if (c1 != 0.f) {
#pragma unroll
        for (int c = 0; c < 16; ++c) dxv[16 + c] = fmaf(c1, v[c], dxv[16 + c]);
      }
      if (c2 != 0.f) {
#pragma unroll
        for (int c = 0; c < 16; ++c) dxv[32 + c] = fmaf(c2, v[c], dxv[32 + c]);
      }
    }
  }

  const bool pre = (m3 > 0.1f);

  float z = 0.f;
#pragma unroll
  for (int c = 0; c < 48; ++c) z = fmaf(dxv[c], swfr[c], z);
  const float fr = pre ? sigmoidf_(z) : 0.f;

  // gumbel-softmax hard gate (argmax over 2 classes; ties -> class 0)
  const float u0 = bits_to_unit(rng_bits(sk0, sk1, 2u * (uint32_t)p));
  const float u1 = bits_to_unit(rng_bits(sk0, sk1, 2u * (uint32_t)p + 1u));
  const float g0 = -logf(-logf(u0 + 1e-20f) + 1e-20f);
  const float g1 = -logf(-logf(u1 + 1e-20f) + 1e-20f);
  const float d0 = logf(fr + 1e-10f) + g0;
  const float d1 = logf(1.0f - fr + 1e-10f) + g1;
  const bool updb = (d0 >= d1);

  float h[16];
#pragma unroll
  for (int c = 0; c < 16; ++c) h[c] = 0.f;
  if (updb) {
    for (int jj = 0; jj < 256; ++jj) {
      const float* wr = &sw0[jj * 48];
      float acc = sb0[jj];
#pragma unroll
      for (int k = 0; k < 48; ++k) acc = fmaf(wr[k], dxv[k], acc);
      const float r = fmaxf(acc, 0.f);
      const float* w1r = w1t + (jj << 4);
#pragma unroll
      for (int c = 0; c < 16; c += 4) {
        float4 q = *(const float4*)(w1r + c);
        h[c]     = fmaf(q.x, r, h[c]);
        h[c + 1] = fmaf(q.y, r, h[c + 1]);
        h[c + 2] = fmaf(q.z, r, h[c + 2]);
        h[c + 3] = fmaf(q.w, r, h[c + 3]);
      }
    }
  }

  float* dst = xmid + ((size_t)p << 4);
#pragma unroll
  for (int c = 0; c < 16; c += 4) {
    float4 q;
    q.x = dxv[c]     + h[c];
    q.y = dxv[c + 1] + h[c + 1];
    q.z = dxv[c + 2] + h[c + 2];
    q.w = dxv[c + 3] + h[c + 3];
    *(float4*)(dst + c) = q;
  }
  ch3[p]     = dxv[3] + h[3];
  premask[p] = pre ? 1.f : 0.f;
  frout[p]   = fr;
}

// Kernel B: post-alive mask; zero dead pixels in-place in the d_out slice.
__global__ __launch_bounds__(256) void ca_step_b(
    float* __restrict__ xs, const float* __restrict__ ch3,
    const float* __restrict__ premask) {
  const int p   = blockIdx.x * 256 + threadIdx.x;
  const int b   = p >> 14;
  const int rem = p & 16383;
  const int hh  = rem >> 7;
  const int ww  = rem & 127;
  const float* cb = ch3 + (b << 14);
  float m = -INFINITY;
#pragma unroll
  for (int dh = -1; dh <= 1; ++dh) {
    const int h2 = hh + dh;
    if ((unsigned)h2 >= 128u) continue;
#pragma unroll
    for (int dw = -1; dw <= 1; ++dw) {
      const int w2 = ww + dw;
      if ((unsigned)w2 >= 128u) continue;
      m = fmaxf(m, cb[(h2 << 7) + w2]);
    }
  }
  const bool alive = (premask[p] != 0.f) && (m > 0.1f);
  if (!alive) {
    float4 z; z.x = 0.f; z.y = 0.f; z.z = 0.f; z.w = 0.f;
    float* dst = xs + ((size_t)p << 4);
    *(float4*)(dst)      = z;
    *(float4*)(dst + 4)  = z;
    *(float4*)(dst + 8)  = z;
    *(float4*)(dst + 12) = z;
  }
}

__global__ void w1_transpose(const float* __restrict__ w1, float* __restrict__ w1t) {
  const int i = blockIdx.x * 256 + threadIdx.x;
  if (i < 4096) {
    const int c = i >> 8;
    const int jj = i & 255;
    w1t[jj * 16 + c] = w1[i];
  }
}

extern "C" void kernel_launch(void* const* d_in, const int* in_sizes, int n_in,
                              void* d_out, int out_size, void* d_ws, size_t ws_size,
                              hipStream_t stream) {
  const float* x0  = (const float*)d_in[0];
  const float* w0  = (const float*)d_in[1];
  const float* b0  = (const float*)d_in[2];
  const float* w1  = (const float*)d_in[3];
  const float* wfr = (const float*)d_in[4];
  const int steps = 4;  // fixed by setup_inputs

  float* xsteps  = (float*)d_out;
  float* frsteps = xsteps + (size_t)steps * XSLICE;

  float* w1t = (float*)d_ws;        // 4096 f
  float* ch3 = w1t + 4096;          // BHW f
  float* pre = ch3 + BHW;           // BHW f

  // step keys = jax.random.split(jax.random.key(42), 4)
  uint32_t sk[4][2];
#if PARTITIONABLE
  for (int s = 0; s < steps; ++s)
    tf2x32(0u, 42u, 0u, (uint32_t)s, sk[s][0], sk[s][1]);
#else
  {
    uint32_t a[4], bo[4];
    for (int i = 0; i < 4; ++i) tf2x32(0u, 42u, (uint32_t)i, (uint32_t)(i + 4), a[i], bo[i]);
    uint32_t flat[8] = {a[0], a[1], a[2], a[3], bo[0], bo[1], bo[2], bo[3]};
    for (int s = 0; s < 4; ++s) { sk[s][0] = flat[2 * s]; sk[s][1] = flat[2 * s + 1]; }
  }
#endif

  w1_transpose<<<16, 256, 0, stream>>>(w1, w1t);
  for (int s = 0; s < steps; ++s) {
    const float* xin = (s == 0) ? x0 : (xsteps + (size_t)(s - 1) * XSLICE);
    float* xmid = xsteps + (size_t)s * XSLICE;
    ca_step_a<<<1024, 256, 0, stream>>>(xin, w0, b0, w1t, wfr, xmid, ch3, pre,
                                        frsteps + (size_t)s * BHW, sk[s][0], sk[s][1]);
    ca_step_b<<<1024, 256, 0, stream>>>(xmid, ch3, pre);
  }
}

// Round 2
// 697.203 us; speedup vs baseline: 1.0233x; 1.0233x over previous
//
#include <hip/hip_runtime.h>
#include <cstdint>
#include <math.h>

// EnergyCAModel: 4-step neural CA.
// Layouts: x [B=16,H=128,W=128,C=16] f32. Out = x_steps [4*16*128*128*16] ++ fr_steps [4*16*128*128].
#define HW2    16384      // 128*128
#define BHW    262144     // 16*128*128
#define XSLICE 4194304    // BHW*16

// 1 = modern JAX (jax_threefry_partitionable=True, default since 0.4.36) -- verified passing R1
#define PARTITIONABLE 1

__host__ __device__ static inline uint32_t rotl32(uint32_t v, int r) {
  return (v << r) | (v >> (32 - r));
}

// Exact JAX Threefry-2x32 (20 rounds).
__host__ __device__ static inline void tf2x32(uint32_t k0, uint32_t k1,
                                              uint32_t x0, uint32_t x1,
                                              uint32_t& o0, uint32_t& o1) {
  uint32_t ks2 = k0 ^ k1 ^ 0x1BD11BDAu;
  x0 += k0; x1 += k1;
#define TFR(r) { x0 += x1; x1 = rotl32(x1, (r)); x1 ^= x0; }
  TFR(13) TFR(15) TFR(26) TFR(6)   x0 += k1;  x1 += ks2 + 1u;
  TFR(17) TFR(29) TFR(16) TFR(24)  x0 += ks2; x1 += k0 + 2u;
  TFR(13) TFR(15) TFR(26) TFR(6)   x0 += k0;  x1 += k1 + 3u;
  TFR(17) TFR(29) TFR(16) TFR(24)  x0 += k1;  x1 += ks2 + 4u;
  TFR(13) TFR(15) TFR(26) TFR(6)   x0 += ks2; x1 += k0 + 5u;
#undef TFR
  o0 = x0; o1 = x1;
}

__device__ static inline float bits_to_unit(uint32_t bits) {
  // jax.random.uniform: bitcast((bits>>9)|0x3f800000) - 1.0  -> [0,1)
  return __uint_as_float((bits >> 9) | 0x3f800000u) - 1.0f;
}

// random bits for flat element f of a 524288-element uniform draw
__device__ static inline uint32_t rng_bits(uint32_t sk0, uint32_t sk1, uint32_t f) {
  uint32_t o0, o1;
  tf2x32(sk0, sk1, 0u, f, o0, o1);
  return o0 ^ o1;
}

__device__ static inline float sigmoidf_(float z) {
  if (z >= 0.f) { float e = expf(-z); return 1.f / (1.f + e); }
  float e = expf(z); return e / (1.f + e);
}

// Kernel A: per pixel -> sobel features, pre-alive, fr, gumbel gate, MLP, x_mid.
// All weight reads are wave-uniform -> compiler emits s_load (scalar pipe),
// freeing the VALU issue slots that LDS broadcast reads used to consume.
__global__ __launch_bounds__(256) void ca_step_a(
    const float* __restrict__ xin,   // [B,H,W,16]
    const float* __restrict__ w0g,   // [256,48]
    const float* __restrict__ b0g,   // [256]
    const float* __restrict__ w1t,   // [256,16]  (w1 transposed)
    const float* __restrict__ wfrg,  // [48]
    float* __restrict__ xmid,        // d_out x-slice for this step
    float* __restrict__ ch3,         // [BHW] updated channel-3 plane
    float* __restrict__ premask,     // [BHW]
    float* __restrict__ frout,       // [BHW] fr output slice
    uint32_t sk0, uint32_t sk1) {
  const int tid = threadIdx.x;
  const int p   = blockIdx.x * 256 + tid;
  const int b   = p >> 14;
  const int rem = p & 16383;
  const int hh  = rem >> 7;
  const int ww  = rem & 127;

  // dxv = [x(16), y1(16), y2(16)]
  float dxv[48];
#pragma unroll
  for (int c = 0; c < 48; ++c) dxv[c] = 0.f;
  float m3 = -INFINITY;

  const float* base = xin + ((size_t)b << 18);
#pragma unroll
  for (int dh = -1; dh <= 1; ++dh) {
    const int j = dh + 1;              // H kernel index
    const int h2 = hh + dh;
    const bool hok = ((unsigned)h2 < 128u);
#pragma unroll
    for (int dw = -1; dw <= 1; ++dw) {
      const int i = dw + 1;            // W kernel index
      const int w2 = ww + dw;
      float v[16];
      if (hok && ((unsigned)w2 < 128u)) {
        const float* s = base + (((h2 << 7) + w2) << 4);
#pragma unroll
        for (int c = 0; c < 16; c += 4) {
          float4 q = *(const float4*)(s + c);
          v[c] = q.x; v[c + 1] = q.y; v[c + 2] = q.z; v[c + 3] = q.w;
        }
        m3 = fmaxf(m3, v[3]);
      } else {
#pragma unroll
        for (int c = 0; c < 16; ++c) v[c] = 0.f;
      }
      // y1: smooth[1,2,1] over W, diff[-1,0,1] over H;  y2: transposed (angle=0)
      const float smv[3] = {1.f, 2.f, 1.f};
      const float dfv[3] = {-1.f, 0.f, 1.f};
      const float c1 = smv[i] * dfv[j] * 0.125f;
      const float c2 = dfv[i] * smv[j] * 0.125f;
      if (dh == 0 && dw == 0) {
#pragma unroll
        for (int c = 0; c < 16; ++c) dxv[c] = v[c];
      }
      if (c1 != 0.f) {
#pragma unroll
        for (int c = 0; c < 16; ++c) dxv[16 + c] = fmaf(c1, v[c], dxv[16 + c]);
      }
      if (c2 != 0.f) {
#pragma unroll
        for (int c = 0; c < 16; ++c) dxv[32 + c] = fmaf(c2, v[c], dxv[32 + c]);
      }
    }
  }

  const bool pre = (m3 > 0.1f);

  float z = 0.f;
#pragma unroll
  for (int c = 0; c < 48; ++c) z = fmaf(dxv[c], wfrg[c], z);
  const float fr = pre ? sigmoidf_(z) : 0.f;

  // gumbel-softmax hard gate (argmax over 2 classes; ties -> class 0)
  const float u0 = bits_to_unit(rng_bits(sk0, sk1, 2u * (uint32_t)p));
  const float u1 = bits_to_unit(rng_bits(sk0, sk1, 2u * (uint32_t)p + 1u));
  const float g0 = -logf(-logf(u0 + 1e-20f) + 1e-20f);
  const float g1 = -logf(-logf(u1 + 1e-20f) + 1e-20f);
  const float d0 = logf(fr + 1e-10f) + g0;
  const float d1 = logf(1.0f - fr + 1e-10f) + g1;
  const bool updb = (d0 >= d1);

  float h[16];
#pragma unroll
  for (int c = 0; c < 16; ++c) h[c] = 0.f;
  if (updb) {
    for (int jj = 0; jj < 256; ++jj) {
      const float* __restrict__ wr = w0g + jj * 48;   // uniform -> s_load_dwordx16 x3
      float a0 = 0.f, a1 = 0.f, a2 = 0.f, a3 = 0.f;   // 4 chains for ILP
#pragma unroll
      for (int k = 0; k < 48; k += 4) {
        a0 = fmaf(wr[k + 0], dxv[k + 0], a0);
        a1 = fmaf(wr[k + 1], dxv[k + 1], a1);
        a2 = fmaf(wr[k + 2], dxv[k + 2], a2);
        a3 = fmaf(wr[k + 3], dxv[k + 3], a3);
      }
      const float r = fmaxf(b0g[jj] + ((a0 + a1) + (a2 + a3)), 0.f);
      const float* __restrict__ w1r = w1t + (jj << 4); // uniform -> s_load_dwordx16
#pragma unroll
      for (int c = 0; c < 16; ++c) h[c] = fmaf(w1r[c], r, h[c]);
    }
  }

  float* dst = xmid + ((size_t)p << 4);
#pragma unroll
  for (int c = 0; c < 16; c += 4) {
    float4 q;
    q.x = dxv[c]     + h[c];
    q.y = dxv[c + 1] + h[c + 1];
    q.z = dxv[c + 2] + h[c + 2];
    q.w = dxv[c + 3] + h[c + 3];
    *(float4*)(dst + c) = q;
  }
  ch3[p]     = dxv[3] + h[3];
  premask[p] = pre ? 1.f : 0.f;
  frout[p]   = fr;
}

// Kernel B: post-alive mask; zero dead pixels in-place in the d_out slice.
__global__ __launch_bounds__(256) void ca_step_b(
    float* __restrict__ xs, const float* __restrict__ ch3,
    const float* __restrict__ premask) {
  const int p   = blockIdx.x * 256 + threadIdx.x;
  const int b   = p >> 14;
  const int rem = p & 16383;
  const int hh  = rem >> 7;
  const int ww  = rem & 127;
  const float* cb = ch3 + (b << 14);
  float m = -INFINITY;
#pragma unroll
  for (int dh = -1; dh <= 1; ++dh) {
    const int h2 = hh + dh;
    if ((unsigned)h2 >= 128u) continue;
#pragma unroll
    for (int dw = -1; dw <= 1; ++dw) {
      const int w2 = ww + dw;
      if ((unsigned)w2 >= 128u) continue;
      m = fmaxf(m, cb[(h2 << 7) + w2]);
    }
  }
  const bool alive = (premask[p] != 0.f) && (m > 0.1f);
  if (!alive) {
    float4 z; z.x = 0.f; z.y = 0.f; z.z = 0.f; z.w = 0.f;
    float* dst = xs + ((size_t)p << 4);
    *(float4*)(dst)      = z;
    *(float4*)(dst + 4)  = z;
    *(float4*)(dst + 8)  = z;
    *(float4*)(dst + 12) = z;
  }
}

__global__ void w1_transpose(const float* __restrict__ w1, float* __restrict__ w1t) {
  const int i = blockIdx.x * 256 + threadIdx.x;
  if (i < 4096) {
    const int c = i >> 8;
    const int jj = i & 255;
    w1t[jj * 16 + c] = w1[i];
  }
}

extern "C" void kernel_launch(void* const* d_in, const int* in_sizes, int n_in,
                              void* d_out, int out_size, void* d_ws, size_t ws_size,
                              hipStream_t stream) {
  const float* x0  = (const float*)d_in[0];
  const float* w0  = (const float*)d_in[1];
  const float* b0  = (const float*)d_in[2];
  const float* w1  = (const float*)d_in[3];
  const float* wfr = (const float*)d_in[4];
  const int steps = 4;  // fixed by setup_inputs

  float* xsteps  = (float*)d_out;
  float* frsteps = xsteps + (size_t)steps * XSLICE;

  float* w1t = (float*)d_ws;        // 4096 f
  float* ch3 = w1t + 4096;          // BHW f
  float* pre = ch3 + BHW;           // BHW f

  // step keys = jax.random.split(jax.random.key(42), 4) (partitionable threefry)
  uint32_t sk[4][2];
  for (int s = 0; s < steps; ++s)
    tf2x32(0u, 42u, 0u, (uint32_t)s, sk[s][0], sk[s][1]);

  w1_transpose<<<16, 256, 0, stream>>>(w1, w1t);
  for (int s = 0; s < steps; ++s) {
    const float* xin = (s == 0) ? x0 : (xsteps + (size_t)(s - 1) * XSLICE);
    float* xmid = xsteps + (size_t)s * XSLICE;
    ca_step_a<<<1024, 256, 0, stream>>>(xin, w0, b0, w1t, wfr, xmid, ch3, pre,
                                        frsteps + (size_t)s * BHW, sk[s][0], sk[s][1]);
    ca_step_b<<<1024, 256, 0, stream>>>(xmid, ch3, pre);
  }
}

// Round 3
// 505.078 us; speedup vs baseline: 1.4126x; 1.3804x over previous
//
#include <hip/hip_runtime.h>
#include <cstdint>
#include <math.h>

// EnergyCAModel: 4-step neural CA.
// x [B=16,H=128,W=128,C=16] f32. Out = x_steps [4*16*128*128*16] ++ fr_steps [4*16*128*128].
#define HW2    16384      // 128*128
#define BHW    262144     // 16*128*128
#define XSLICE 4194304    // BHW*16

__host__ __device__ static inline uint32_t rotl32(uint32_t v, int r) {
  return (v << r) | (v >> (32 - r));
}

// Exact JAX Threefry-2x32 (20 rounds), partitionable layout (verified R1).
__host__ __device__ static inline void tf2x32(uint32_t k0, uint32_t k1,
                                              uint32_t x0, uint32_t x1,
                                              uint32_t& o0, uint32_t& o1) {
  uint32_t ks2 = k0 ^ k1 ^ 0x1BD11BDAu;
  x0 += k0; x1 += k1;
#define TFR(r) { x0 += x1; x1 = rotl32(x1, (r)); x1 ^= x0; }
  TFR(13) TFR(15) TFR(26) TFR(6)   x0 += k1;  x1 += ks2 + 1u;
  TFR(17) TFR(29) TFR(16) TFR(24)  x0 += ks2; x1 += k0 + 2u;
  TFR(13) TFR(15) TFR(26) TFR(6)   x0 += k0;  x1 += k1 + 3u;
  TFR(17) TFR(29) TFR(16) TFR(24)  x0 += k1;  x1 += ks2 + 4u;
  TFR(13) TFR(15) TFR(26) TFR(6)   x0 += ks2; x1 += k0 + 5u;
#undef TFR
  o0 = x0; o1 = x1;
}

__device__ static inline float bits_to_unit(uint32_t bits) {
  return __uint_as_float((bits >> 9) | 0x3f800000u) - 1.0f;  // [0,1)
}

__device__ static inline uint32_t rng_bits(uint32_t sk0, uint32_t sk1, uint32_t f) {
  uint32_t o0, o1;
  tf2x32(sk0, sk1, 0u, f, o0, o1);
  return o0 ^ o1;
}

__device__ static inline float sigmoidf_(float z) {
  if (z >= 0.f) { float e = expf(-z); return 1.f / (1.f + e); }
  float e = expf(z); return e / (1.f + e);
}

// Sobel features + pre-alive max for one pixel.
__device__ static inline void sobel_feat(const float* __restrict__ base,
                                         int hh, int ww, float* dxv, float& m3) {
#pragma unroll
  for (int c = 0; c < 48; ++c) dxv[c] = 0.f;
  m3 = -INFINITY;
#pragma unroll
  for (int dh = -1; dh <= 1; ++dh) {
    const int j = dh + 1;
    const int h2 = hh + dh;
    const bool hok = ((unsigned)h2 < 128u);
#pragma unroll
    for (int dw = -1; dw <= 1; ++dw) {
      const int i = dw + 1;
      const int w2 = ww + dw;
      float v[16];
      if (hok && ((unsigned)w2 < 128u)) {
        const float* s = base + (((h2 << 7) + w2) << 4);
#pragma unroll
        for (int c = 0; c < 16; c += 4) {
          float4 q = *(const float4*)(s + c);
          v[c] = q.x; v[c + 1] = q.y; v[c + 2] = q.z; v[c + 3] = q.w;
        }
        m3 = fmaxf(m3, v[3]);
      } else {
#pragma unroll
        for (int c = 0; c < 16; ++c) v[c] = 0.f;
      }
      const float smv[3] = {1.f, 2.f, 1.f};
      const float dfv[3] = {-1.f, 0.f, 1.f};
      const float c1 = smv[i] * dfv[j] * 0.125f;  // y1
      const float c2 = dfv[i] * smv[j] * 0.125f;  // y2
      if (dh == 0 && dw == 0) {
#pragma unroll
        for (int c = 0; c < 16; ++c) dxv[c] = v[c];
      }
      if (c1 != 0.f) {
#pragma unroll
        for (int c = 0; c < 16; ++c) dxv[16 + c] = fmaf(c1, v[c], dxv[16 + c]);
      }
      if (c2 != 0.f) {
#pragma unroll
        for (int c = 0; c < 16; ++c) dxv[32 + c] = fmaf(c2, v[c], dxv[32 + c]);
      }
    }
  }
}

// Kernel A: 2 pixels/thread. Weights packed in LDS rows [w0(48)|b0|pad3|w1t(16)],
// streamed in two 128-neuron passes; all inner-loop reads are LDS broadcasts.
__global__ __launch_bounds__(256, 2) void ca_step_a(
    const float* __restrict__ xin,   // [B,H,W,16]
    const float* __restrict__ w0g,   // [256,48]
    const float* __restrict__ b0g,   // [256]
    const float* __restrict__ w1g,   // [16,256]
    const float* __restrict__ wfrg,  // [48]
    float* __restrict__ xmid,
    float* __restrict__ ch3,
    float* __restrict__ premask,
    float* __restrict__ frout,
    uint32_t sk0, uint32_t sk1) {
  __shared__ float sw[128 * 68];   // 34.8 KB

  const int tid = threadIdx.x;
  const int p0  = blockIdx.x * 512 + tid;
  const int p1  = p0 + 256;
  const int b   = p0 >> 14;                 // both pixels in same image
  const int rem = p0 & 16383;
  const int hh0 = rem >> 7;
  const int ww0 = rem & 127;
  const int hh1 = hh0 + 2;                  // p1 = p0 + 256 -> +2 rows

  const float* base = xin + ((size_t)b << 18);

  float dx0[48], dx1[48];
  float m30, m31;
  sobel_feat(base, hh0, ww0, dx0, m30);
  sobel_feat(base, hh1, ww0, dx1, m31);

  const bool pre0 = (m30 > 0.1f);
  const bool pre1 = (m31 > 0.1f);

  float z0 = 0.f, z1 = 0.f;
#pragma unroll
  for (int c = 0; c < 48; ++c) {
    z0 = fmaf(dx0[c], wfrg[c], z0);
    z1 = fmaf(dx1[c], wfrg[c], z1);
  }
  const float fr0 = pre0 ? sigmoidf_(z0) : 0.f;
  const float fr1 = pre1 ? sigmoidf_(z1) : 0.f;

  // gumbel gate (exact threefry; argmax over 2 classes, ties -> class 0)
  float upd0, upd1;
  {
    const float u0 = bits_to_unit(rng_bits(sk0, sk1, 2u * (uint32_t)p0));
    const float u1 = bits_to_unit(rng_bits(sk0, sk1, 2u * (uint32_t)p0 + 1u));
    const float d0 = logf(fr0 + 1e-10f) - logf(-logf(u0 + 1e-20f) + 1e-20f);
    const float d1 = logf(1.0f - fr0 + 1e-10f) - logf(-logf(u1 + 1e-20f) + 1e-20f);
    upd0 = (d0 >= d1) ? 1.f : 0.f;
  }
  {
    const float u0 = bits_to_unit(rng_bits(sk0, sk1, 2u * (uint32_t)p1));
    const float u1 = bits_to_unit(rng_bits(sk0, sk1, 2u * (uint32_t)p1 + 1u));
    const float d0 = logf(fr1 + 1e-10f) - logf(-logf(u0 + 1e-20f) + 1e-20f);
    const float d1 = logf(1.0f - fr1 + 1e-10f) - logf(-logf(u1 + 1e-20f) + 1e-20f);
    upd1 = (d0 >= d1) ? 1.f : 0.f;
  }

  float h0[16], h1[16];
#pragma unroll
  for (int c = 0; c < 16; ++c) { h0[c] = 0.f; h1[c] = 0.f; }

  for (int pass = 0; pass < 2; ++pass) {
    const int jb = pass << 7;
    if (pass) __syncthreads();  // previous pass fully consumed
    // ---- stage 128 packed rows ----
    {
      const float4* w04 = (const float4*)w0g;
      float4* sw4 = (float4*)sw;
      for (int i = tid; i < 1536; i += 256) {          // w0 rows
        const int j = i / 12, q = i - j * 12;
        sw4[j * 17 + q] = w04[(jb + j) * 12 + q];
      }
      if (tid < 128) sw[tid * 68 + 48] = b0g[jb + tid];  // b0
      for (int i = tid; i < 2048; i += 256) {            // w1^T
        const int j = i & 127, c = i >> 7;
        sw[j * 68 + 52 + c] = w1g[c * 256 + jb + j];
      }
    }
    __syncthreads();
    // ---- 128 neurons ----
#pragma unroll 2
    for (int jj = 0; jj < 128; ++jj) {
      const float* row = sw + jj * 68;
      float a00 = 0.f, a01 = 0.f, a10 = 0.f, a11 = 0.f;
#pragma unroll
      for (int k = 0; k < 48; k += 8) {
        const float4 wa = *(const float4*)(row + k);
        const float4 wb = *(const float4*)(row + k + 4);
        a00 = fmaf(wa.x, dx0[k + 0], a00); a01 = fmaf(wa.y, dx0[k + 1], a01);
        a00 = fmaf(wa.z, dx0[k + 2], a00); a01 = fmaf(wa.w, dx0[k + 3], a01);
        a00 = fmaf(wb.x, dx0[k + 4], a00); a01 = fmaf(wb.y, dx0[k + 5], a01);
        a00 = fmaf(wb.z, dx0[k + 6], a00); a01 = fmaf(wb.w, dx0[k + 7], a01);
        a10 = fmaf(wa.x, dx1[k + 0], a10); a11 = fmaf(wa.y, dx1[k + 1], a11);
        a10 = fmaf(wa.z, dx1[k + 2], a10); a11 = fmaf(wa.w, dx1[k + 3], a11);
        a10 = fmaf(wb.x, dx1[k + 4], a10); a11 = fmaf(wb.y, dx1[k + 5], a11);
        a10 = fmaf(wb.z, dx1[k + 6], a10); a11 = fmaf(wb.w, dx1[k + 7], a11);
      }
      const float bb = row[48];
      const float r0 = fmaxf(bb + (a00 + a01), 0.f);
      const float r1 = fmaxf(bb + (a10 + a11), 0.f);
#pragma unroll
      for (int c = 0; c < 16; c += 4) {
        const float4 q = *(const float4*)(row + 52 + c);
        h0[c]     = fmaf(q.x, r0, h0[c]);     h1[c]     = fmaf(q.x, r1, h1[c]);
        h0[c + 1] = fmaf(q.y, r0, h0[c + 1]); h1[c + 1] = fmaf(q.y, r1, h1[c + 1]);
        h0[c + 2] = fmaf(q.z, r0, h0[c + 2]); h1[c + 2] = fmaf(q.z, r1, h1[c + 2]);
        h0[c + 3] = fmaf(q.w, r0, h0[c + 3]); h1[c + 3] = fmaf(q.w, r1, h1[c + 3]);
      }
    }
  }

  // exact gate: add h only where gumbel picked class 0
  float* dst0 = xmid + ((size_t)p0 << 4);
  float* dst1 = xmid + ((size_t)p1 << 4);
#pragma unroll
  for (int c = 0; c < 16; c += 4) {
    float4 q0, q1;
    q0.x = fmaf(upd0, h0[c],     dx0[c]);     q1.x = fmaf(upd1, h1[c],     dx1[c]);
    q0.y = fmaf(upd0, h0[c + 1], dx0[c + 1]); q1.y = fmaf(upd1, h1[c + 1], dx1[c + 1]);
    q0.z = fmaf(upd0, h0[c + 2], dx0[c + 2]); q1.z = fmaf(upd1, h1[c + 2], dx1[c + 2]);
    q0.w = fmaf(upd0, h0[c + 3], dx0[c + 3]); q1.w = fmaf(upd1, h1[c + 3], dx1[c + 3]);
    *(float4*)(dst0 + c) = q0;
    *(float4*)(dst1 + c) = q1;
  }
  ch3[p0]     = fmaf(upd0, h0[3], dx0[3]);
  ch3[p1]     = fmaf(upd1, h1[3], dx1[3]);
  premask[p0] = pre0 ? 1.f : 0.f;
  premask[p1] = pre1 ? 1.f : 0.f;
  frout[p0]   = fr0;
  frout[p1]   = fr1;
}

// Kernel B: post-alive mask; zero dead pixels in-place in the d_out slice.
__global__ __launch_bounds__(256) void ca_step_b(
    float* __restrict__ xs, const float* __restrict__ ch3,
    const float* __restrict__ premask) {
  const int p   = blockIdx.x * 256 + threadIdx.x;
  const int b   = p >> 14;
  const int rem = p & 16383;
  const int hh  = rem >> 7;
  const int ww  = rem & 127;
  const float* cb = ch3 + (b << 14);
  float m = -INFINITY;
#pragma unroll
  for (int dh = -1; dh <= 1; ++dh) {
    const int h2 = hh + dh;
    if ((unsigned)h2 >= 128u) continue;
#pragma unroll
    for (int dw = -1; dw <= 1; ++dw) {
      const int w2 = ww + dw;
      if ((unsigned)w2 >= 128u) continue;
      m = fmaxf(m, cb[(h2 << 7) + w2]);
    }
  }
  const bool alive = (premask[p] != 0.f) && (m > 0.1f);
  if (!alive) {
    float4 z; z.x = 0.f; z.y = 0.f; z.z = 0.f; z.w = 0.f;
    float* dst = xs + ((size_t)p << 4);
    *(float4*)(dst)      = z;
    *(float4*)(dst + 4)  = z;
    *(float4*)(dst + 8)  = z;
    *(float4*)(dst + 12) = z;
  }
}

extern "C" void kernel_launch(void* const* d_in, const int* in_sizes, int n_in,
                              void* d_out, int out_size, void* d_ws, size_t ws_size,
                              hipStream_t stream) {
  const float* x0  = (const float*)d_in[0];
  const float* w0  = (const float*)d_in[1];
  const float* b0  = (const float*)d_in[2];
  const float* w1  = (const float*)d_in[3];
  const float* wfr = (const float*)d_in[4];
  const int steps = 4;

  float* xsteps  = (float*)d_out;
  float* frsteps = xsteps + (size_t)steps * XSLICE;

  float* ch3 = (float*)d_ws;        // BHW f
  float* pre = ch3 + BHW;           // BHW f

  // step keys = jax.random.split(jax.random.key(42), 4) (partitionable threefry)
  uint32_t sk[4][2];
  for (int s = 0; s < steps; ++s)
    tf2x32(0u, 42u, 0u, (uint32_t)s, sk[s][0], sk[s][1]);

  for (int s = 0; s < steps; ++s) {
    const float* xin = (s == 0) ? x0 : (xsteps + (size_t)(s - 1) * XSLICE);
    float* xmid = xsteps + (size_t)s * XSLICE;
    ca_step_a<<<512, 256, 0, stream>>>(xin, w0, b0, w1, wfr, xmid, ch3, pre,
                                       frsteps + (size_t)s * BHW, sk[s][0], sk[s][1]);
    ca_step_b<<<1024, 256, 0, stream>>>(xmid, ch3, pre);
  }
}